// Round 2
// baseline (1152.238 us; speedup 1.0000x reference)
//
#include <hip/hip_runtime.h>
#include <hip/hip_bf16.h>

// ---------------- problem constants ----------------
static constexpr float EPS_   = 1e-6f;
static constexpr float SCALE_ = 0.07216878364870323f;  // 192^-0.5
static constexpr float LOG2_1E4_OVER_32 = 13.287712379549449f / 32.0f;

// ---------------- workspace layout (float offsets) ----------------
static constexpr long OFF_QLAT = 0;                        // 64*1536
static constexpr long OFF_Q    = OFF_QLAT + 64L * 1536;    // 64*6144
static constexpr long OFF_KVR  = OFF_Q    + 64L * 6144;    // 64*192
static constexpr long OFF_O    = OFF_KVR  + 64L * 192;     // 64*6144
static constexpr long OFF_LAT  = OFF_O    + 64L * 6144;    // 64*4096
static constexpr long ZERO_F   = OFF_LAT  + 64L * 4096;    // zero [0, ZERO_F)
static constexpr long OFF_SELM = ZERO_F;                   // 2048
static constexpr long OFF_SELI = OFF_SELM + 2048;          // 2048
static constexpr long OFF_SELT = OFF_SELI + 2048;          // 2048 (uint bits)
static constexpr long OFF_LOG  = OFF_SELT + 2048;          // 64*32*4096

// ---------------- helpers ----------------
__device__ __forceinline__ unsigned fkey(float f) {
    unsigned u = __float_as_uint(f);
    return (u & 0x80000000u) ? ~u : (u | 0x80000000u);
}
__device__ __forceinline__ float kval(unsigned k) {
    unsigned u = (k & 0x80000000u) ? (k ^ 0x80000000u) : ~k;
    return __uint_as_float(u);
}

// ============================================================
// Generic skinny GEMM: C[64 x M] += X[64 x K] * W[M x K]^T
// grid: (M/TN, K/kslice, batch) ; 256 threads; atomicAdd epilogue
// ============================================================
template <int TN>
__global__ __launch_bounds__(256) void gemm_xwt(
    const float* __restrict__ Xb, const float* __restrict__ Wb,
    float* __restrict__ Cb, int K, int ldX, int ldC, int kslice,
    long sXz, long sWz, long sCz)
{
    const float* X = Xb + (long)blockIdx.z * sXz;
    const float* W = Wb + (long)blockIdx.z * sWz;
    float*       C = Cb + (long)blockIdx.z * sCz;
    const int col0 = blockIdx.x * TN;
    const int k0   = blockIdx.y * kslice;

    __shared__ float Xs[32][68];        // [k][row]
    __shared__ float Ws[32][TN + 4];    // [k][col]

    const int t  = threadIdx.x;
    constexpr int CW = TN / 16;         // cols per thread (8 or 4)
    const int r0 = (t & 15) * 4;
    const int c0 = (t >> 4) * CW;

    float acc[4][CW];
#pragma unroll
    for (int j = 0; j < 4; ++j)
#pragma unroll
        for (int m = 0; m < CW; ++m) acc[j][m] = 0.f;

    for (int kt = k0; kt < k0 + kslice; kt += 32) {
        // stage X tile (64 rows x 32 k)
#pragma unroll
        for (int i = 0; i < 2; ++i) {
            int f = t + i * 256;
            int r = f >> 3, k4 = (f & 7) * 4;
            float4 v = *(const float4*)(X + (long)r * ldX + kt + k4);
            Xs[k4][r] = v.x; Xs[k4 + 1][r] = v.y; Xs[k4 + 2][r] = v.z; Xs[k4 + 3][r] = v.w;
        }
        // stage W tile (TN cols x 32 k)
#pragma unroll
        for (int i = 0; i < TN / 32; ++i) {
            int f = t + i * 256;
            int c = f >> 3, k4 = (f & 7) * 4;
            float4 v = *(const float4*)(W + (long)(col0 + c) * K + kt + k4);
            Ws[k4][c] = v.x; Ws[k4 + 1][c] = v.y; Ws[k4 + 2][c] = v.z; Ws[k4 + 3][c] = v.w;
        }
        __syncthreads();
#pragma unroll
        for (int k = 0; k < 32; ++k) {
            float4 a4 = *(const float4*)&Xs[k][r0];
            float av[4] = {a4.x, a4.y, a4.z, a4.w};
            float bv[CW];
#pragma unroll
            for (int m0 = 0; m0 < CW; m0 += 4) {
                float4 b4 = *(const float4*)&Ws[k][c0 + m0];
                bv[m0] = b4.x; bv[m0 + 1] = b4.y; bv[m0 + 2] = b4.z; bv[m0 + 3] = b4.w;
            }
#pragma unroll
            for (int j = 0; j < 4; ++j)
#pragma unroll
                for (int m = 0; m < CW; ++m) acc[j][m] += av[j] * bv[m];
        }
        __syncthreads();
    }
#pragma unroll
    for (int j = 0; j < 4; ++j)
#pragma unroll
        for (int m = 0; m < CW; ++m)
            atomicAdd(&C[(long)(r0 + j) * ldC + col0 + c0 + m], acc[j][m]);
}

// ============================================================
// RMS norm over rows (in-place). grid = rows, 256 threads.
// ============================================================
__global__ __launch_bounds__(256) void rms_rows(
    float* __restrict__ x, const float* __restrict__ w, int len)
{
    __shared__ float fred[4];
    float* row = x + (long)blockIdx.x * len;
    int t = threadIdx.x;
    float ss = 0.f;
    for (int l = t; l < len; l += 256) { float v = row[l]; ss += v * v; }
#pragma unroll
    for (int off = 32; off; off >>= 1) ss += __shfl_xor(ss, off, 64);
    if ((t & 63) == 0) fred[t >> 6] = ss;
    __syncthreads();
    ss = fred[0] + fred[1] + fred[2] + fred[3];
    float scale = rsqrtf(ss / (float)len + EPS_);
    for (int l = t; l < len; l += 256) row[l] = row[l] * scale * w[l];
}

// ============================================================
// RoPE on q[n, 32 heads, dims 128..191]. grid = 64, 256 threads.
// ============================================================
__global__ __launch_bounds__(256) void rope_q(float* __restrict__ q,
                                              const int* __restrict__ cl)
{
    int n = blockIdx.x;
    float pos = (float)(cl[n] - 1);
    int t = threadIdx.x;
#pragma unroll
    for (int i = 0; i < 4; ++i) {
        int f = t + i * 256;           // 32h * 32 pairs = 1024
        int h = f >> 5, r = f & 31;
        float inv = exp2f(-(float)r * LOG2_1E4_OVER_32);
        float ang = pos * inv;
        float sn, cs;
        sincosf(ang, &sn, &cs);
        float* p = q + (long)n * 6144 + h * 192 + 128 + 2 * r;
        float x0 = p[0], x1 = p[1];
        p[0] = x0 * cs - x1 * sn;
        p[1] = x0 * sn + x1 * cs;
    }
}

// ============================================================
// KV post: RMS + RoPE + scatter into cache. grid = 64, 256 threads.
// ============================================================
__global__ __launch_bounds__(256) void kv_post(
    const float* __restrict__ kvr, const float* __restrict__ wnorm,
    const int* __restrict__ cl, const int* __restrict__ smap,
    float* __restrict__ kvcache)
{
    __shared__ float s[192];
    __shared__ float fred[4];
    int n = blockIdx.x, t = threadIdx.x;
    float v = (t < 192) ? kvr[(long)n * 192 + t] : 0.f;
    float ss = v * v;
#pragma unroll
    for (int off = 32; off; off >>= 1) ss += __shfl_xor(ss, off, 64);
    if ((t & 63) == 0) fred[t >> 6] = ss;
    __syncthreads();
    ss = fred[0] + fred[1] + fred[2] + fred[3];
    float scale = rsqrtf(ss / 192.f + EPS_);
    if (t < 192) s[t] = v * scale * wnorm[t];
    __syncthreads();
    if (t < 32) {
        float pos = (float)(cl[n] - 1);
        float inv = exp2f(-(float)t * LOG2_1E4_OVER_32);
        float ang = pos * inv;
        float sn, cs;
        sincosf(ang, &sn, &cs);
        float x0 = s[128 + 2 * t], x1 = s[128 + 2 * t + 1];
        s[128 + 2 * t]     = x0 * cs - x1 * sn;
        s[128 + 2 * t + 1] = x0 * sn + x1 * cs;
    }
    __syncthreads();
    if (t < 192) kvcache[(long)smap[n] * 192 + t] = s[t];
}

// ============================================================
// Attention logits: grid (lchunk=128 -> 32, n=64, hgrp=2), 256 thr.
// LDS: q tile (16 heads) + kv tile (64 slots). Stores logits*SCALE.
// ============================================================
__global__ __launch_bounds__(256) void attn_logits(
    const float* __restrict__ q, const float* __restrict__ kvc,
    const int* __restrict__ bt, const int* __restrict__ cl,
    float* __restrict__ logits)
{
    int n = blockIdx.y, base = blockIdx.x * 128, hb = blockIdx.z * 16;
    int ctx = cl[n];
    if (base >= ctx) return;
    int vcount = min(128, ctx - base);

    __shared__ float qs[16][193];
    __shared__ float kvs[64][193];
    int t = threadIdx.x;

    // stage q: 16 heads x 192 = 768 float4
#pragma unroll
    for (int i = 0; i < 3; ++i) {
        int f = t + i * 256;
        int h = f / 48, kk = (f % 48) * 4;
        float4 v = *(const float4*)(q + (long)n * 6144 + (hb + h) * 192 + kk);
        qs[h][kk] = v.x; qs[h][kk + 1] = v.y; qs[h][kk + 2] = v.z; qs[h][kk + 3] = v.w;
    }

    int h0 = (t >> 5) * 2;     // 8 head-groups of 2
    int l0 = (t & 31) * 2;     // 32 l-groups of 2

    for (int sc = 0; sc < 2; ++sc) {
        int lb = sc * 64;
        int scount = vcount - lb;
        if (scount <= 0) break;
        if (scount > 64) scount = 64;
        __syncthreads();
        // stage kv rows [base+lb, base+lb+scount)
#pragma unroll
        for (int i = 0; i < 12; ++i) {
            int f = t + i * 256;
            int r = f / 48, kk = (f % 48) * 4;
            if (r < scount) {
                int gl = base + lb + r;
                int slot = bt[n * 64 + (gl >> 6)] * 64 + (gl & 63);
                float4 v = *(const float4*)(kvc + (long)slot * 192 + kk);
                kvs[r][kk] = v.x; kvs[r][kk + 1] = v.y; kvs[r][kk + 2] = v.z; kvs[r][kk + 3] = v.w;
            }
        }
        __syncthreads();
        float a00 = 0.f, a01 = 0.f, a10 = 0.f, a11 = 0.f;
#pragma unroll 4
        for (int k = 0; k < 192; ++k) {
            float q0 = qs[h0][k], q1 = qs[h0 + 1][k];
            float v0 = kvs[l0][k], v1 = kvs[l0 + 1][k];
            a00 += q0 * v0; a01 += q0 * v1;
            a10 += q1 * v0; a11 += q1 * v1;
        }
        long rb = ((long)(n * 32 + hb + h0)) * 4096 + base + lb;
        if (l0 < scount) {
            logits[rb + l0]        = a00 * SCALE_;
            logits[rb + 4096 + l0] = a10 * SCALE_;
        }
        if (l0 + 1 < scount) {
            logits[rb + l0 + 1]        = a01 * SCALE_;
            logits[rb + 4096 + l0 + 1] = a11 * SCALE_;
        }
    }
}

// ============================================================
// Exact top-1024 threshold via 4-round radix select + softmax stats.
// grid = 2048 (n*32+h), 256 threads.
// ============================================================
__global__ __launch_bounds__(256) void select_topk(
    const float* __restrict__ logits, const int* __restrict__ cl,
    const float* __restrict__ sink, float* __restrict__ selm,
    float* __restrict__ seli, unsigned* __restrict__ selt)
{
    int nh = blockIdx.x, n = nh >> 5, h = nh & 31;
    int ctx = cl[n];
    const float* row = logits + ((long)nh << 12);

    __shared__ unsigned keys[4096];
    __shared__ int hist[256];
    __shared__ float fred[4];
    __shared__ unsigned s_pref;
    __shared__ int s_R;

    int t = threadIdx.x;
    float mx = -3.0e38f;
    for (int l = t; l < ctx; l += 256) {
        float v = row[l];
        keys[l] = fkey(v);
        mx = fmaxf(mx, v);
    }
#pragma unroll
    for (int off = 32; off; off >>= 1) mx = fmaxf(mx, __shfl_xor(mx, off, 64));
    if ((t & 63) == 0) fred[t >> 6] = mx;
    __syncthreads();
    mx = fmaxf(fmaxf(fred[0], fred[1]), fmaxf(fred[2], fred[3]));

    unsigned tau = 0;
    if (ctx > 1024) {
        unsigned pref = 0;
        int R = 1024;
        for (int round = 3; round >= 0; --round) {
            int sh = round * 8;
            hist[t] = 0;  // 256 threads == 256 bins
            __syncthreads();
            for (int l = t; l < ctx; l += 256) {
                unsigned k = keys[l];
                bool match = (round == 3) || ((k >> (sh + 8)) == (pref >> (sh + 8)));
                if (match) atomicAdd(&hist[(k >> sh) & 255], 1);
            }
            __syncthreads();
            int cum = 0;
            for (int b = t + 1; b < 256; ++b) cum += hist[b];
            if (cum < R && cum + hist[t] >= R) {
                s_pref = pref | ((unsigned)t << sh);
                s_R = R - cum;
            }
            __syncthreads();
            pref = s_pref;
            R = s_R;
            __syncthreads();
        }
        tau = pref;
    }

    float m = fmaxf(mx, sink[h]);
    float part = 0.f;
    for (int l = t; l < ctx; l += 256) {
        unsigned k = keys[l];
        if (k >= tau) part += __expf(kval(k) - m);
    }
#pragma unroll
    for (int off = 32; off; off >>= 1) part += __shfl_xor(part, off, 64);
    __syncthreads();  // protect earlier fred reads
    if ((t & 63) == 0) fred[t >> 6] = part;
    __syncthreads();
    if (t == 0) {
        float denom = fred[0] + fred[1] + fred[2] + fred[3] + __expf(sink[h] - m);
        selm[nh] = m;
        seli[nh] = 1.0f / denom;
        selt[nh] = tau;
    }
}

// ============================================================
// Weighted sum: o[n,h,:] += sum_l p * kv. grid (32, 64, 2), 256 thr.
// ============================================================
__global__ __launch_bounds__(256) void attn_wsum(
    const float* __restrict__ logits, const float* __restrict__ kvc,
    const int* __restrict__ bt, const int* __restrict__ cl,
    const float* __restrict__ selm, const float* __restrict__ seli,
    const unsigned* __restrict__ selt, float* __restrict__ o)
{
    int n = blockIdx.y, base = blockIdx.x * 128, hb = blockIdx.z * 16;
    int ctx = cl[n];
    if (base >= ctx) return;
    int vcount = min(128, ctx - base);

    __shared__ float ps[16][129];
    __shared__ float kvs[64][193];
    int t = threadIdx.x;

    // stage probabilities: 16 h x 128 l
#pragma unroll
    for (int i = 0; i < 8; ++i) {
        int f = t + i * 256;
        int h = f >> 7, l = f & 127;
        float p = 0.f;
        if (l < vcount) {
            int nh = n * 32 + hb + h;
            float v = logits[((long)nh << 12) + base + l];
            if (fkey(v) >= selt[nh]) p = __expf(v - selm[nh]) * seli[nh];
        }
        ps[h][l] = p;
    }

    int h0 = (t >> 5) * 2;    // 8 head-groups of 2
    int d0 = (t & 31) * 6;    // 32 dim-groups of 6
    float acc[2][6];
#pragma unroll
    for (int j = 0; j < 2; ++j)
#pragma unroll
        for (int e = 0; e < 6; ++e) acc[j][e] = 0.f;

    for (int sc = 0; sc < 2; ++sc) {
        int lb = sc * 64;
        int scount = vcount - lb;
        if (scount <= 0) break;
        if (scount > 64) scount = 64;
        __syncthreads();
#pragma unroll
        for (int i = 0; i < 12; ++i) {
            int f = t + i * 256;
            int r = f / 48, kk = (f % 48) * 4;
            if (r < scount) {
                int gl = base + lb + r;
                int slot = bt[n * 64 + (gl >> 6)] * 64 + (gl & 63);
                float4 v = *(const float4*)(kvc + (long)slot * 192 + kk);
                kvs[r][kk] = v.x; kvs[r][kk + 1] = v.y; kvs[r][kk + 2] = v.z; kvs[r][kk + 3] = v.w;
            }
        }
        __syncthreads();
        for (int l = 0; l < scount; ++l) {
            float p0 = ps[h0][lb + l], p1 = ps[h0 + 1][lb + l];
#pragma unroll
            for (int e = 0; e < 6; ++e) {
                float kv = kvs[l][d0 + e];
                acc[0][e] += p0 * kv;
                acc[1][e] += p1 * kv;
            }
        }
    }
#pragma unroll
    for (int j = 0; j < 2; ++j)
#pragma unroll
        for (int e = 0; e < 6; ++e)
            atomicAdd(&o[(long)n * 6144 + (hb + h0 + j) * 192 + d0 + e], acc[j][e]);
}

// ============================================================
// launch
// ============================================================
extern "C" void kernel_launch(void* const* d_in, const int* in_sizes, int n_in,
                              void* d_out, int out_size, void* d_ws, size_t ws_size,
                              hipStream_t stream)
{
    const float* x    = (const float*)d_in[0];
    float*       kvc  = (float*)d_in[1];          // restored by harness each launch
    const int*   bt   = (const int*)d_in[2];
    const int*   cl   = (const int*)d_in[3];
    const int*   smap = (const int*)d_in[4];
    const float* wqa  = (const float*)d_in[5];
    const float* qnw  = (const float*)d_in[6];
    const float* wqb  = (const float*)d_in[7];
    const float* wkv  = (const float*)d_in[8];
    const float* kvnw = (const float*)d_in[9];
    const float* woa  = (const float*)d_in[10];
    const float* wob  = (const float*)d_in[11];
    const float* sink = (const float*)d_in[12];
    float* ws  = (float*)d_ws;
    float* out = (float*)d_out;   // reference output dtype is float32

    // zero the atomic-accumulated regions (ws scratch + final output)
    hipMemsetAsync(ws, 0, (size_t)ZERO_F * sizeof(float), stream);
    hipMemsetAsync(out, 0, (size_t)out_size * sizeof(float), stream);

    // q low-rank: qlat = x @ wq_a^T   (64x1536, K=4096)
    gemm_xwt<128><<<dim3(12, 8, 1), 256, 0, stream>>>(x, wqa, ws + OFF_QLAT,
                                                      4096, 4096, 1536, 512, 0, 0, 0);
    rms_rows<<<64, 256, 0, stream>>>(ws + OFF_QLAT, qnw, 1536);
    // q = qlat @ wq_b^T   (64x6144, K=1536)
    gemm_xwt<128><<<dim3(48, 4, 1), 256, 0, stream>>>(ws + OFF_QLAT, wqb, ws + OFF_Q,
                                                      1536, 1536, 6144, 384, 0, 0, 0);
    rope_q<<<64, 256, 0, stream>>>(ws + OFF_Q, cl);
    // kv = x @ wkv^T   (64x192, K=4096)
    gemm_xwt<64><<<dim3(3, 8, 1), 256, 0, stream>>>(x, wkv, ws + OFF_KVR,
                                                    4096, 4096, 192, 512, 0, 0, 0);
    kv_post<<<64, 256, 0, stream>>>(ws + OFF_KVR, kvnw, cl, smap, kvc);
    // attention
    attn_logits<<<dim3(32, 64, 2), 256, 0, stream>>>(ws + OFF_Q, kvc, bt, cl,
                                                     ws + OFF_LOG);
    select_topk<<<2048, 256, 0, stream>>>(ws + OFF_LOG, cl, sink,
                                          ws + OFF_SELM, ws + OFF_SELI,
                                          (unsigned*)(ws + OFF_SELT));
    attn_wsum<<<dim3(32, 64, 2), 256, 0, stream>>>(ws + OFF_LOG, kvc, bt, cl,
                                                   ws + OFF_SELM, ws + OFF_SELI,
                                                   (unsigned*)(ws + OFF_SELT),
                                                   ws + OFF_O);
    // grouped wo_a: lat[n, g*512+o] = og[n,g,:] @ wo_a[g]^T  (8 batches, 64x512, K=768)
    gemm_xwt<128><<<dim3(4, 2, 8), 256, 0, stream>>>(ws + OFF_O, woa, ws + OFF_LAT,
                                                     768, 6144, 4096, 384,
                                                     768, 512L * 768, 512);
    // out = lat @ wo_b^T  (64x4096, K=4096) — accumulate directly into d_out (f32)
    gemm_xwt<128><<<dim3(32, 8, 1), 256, 0, stream>>>(ws + OFF_LAT, wob, out,
                                                      4096, 4096, 4096, 512, 0, 0, 0);
}

// Round 3
// 768.207 us; speedup vs baseline: 1.4999x; 1.4999x over previous
//
#include <hip/hip_runtime.h>
#include <hip/hip_bf16.h>

// ---------------- problem constants ----------------
static constexpr float EPS_   = 1e-6f;
static constexpr float SCALE_ = 0.07216878364870323f;  // 192^-0.5
static constexpr float LOG2_1E4_OVER_32 = 13.287712379549449f / 32.0f;

// ---------------- workspace layout (float offsets) ----------------
static constexpr long OFF_QLAT = 0;                        // 64*1536
static constexpr long OFF_Q    = OFF_QLAT + 64L * 1536;    // 64*6144
static constexpr long OFF_KVR  = OFF_Q    + 64L * 6144;    // 64*192
static constexpr long OFF_O    = OFF_KVR  + 64L * 192;     // 64*6144
static constexpr long OFF_LAT  = OFF_O    + 64L * 6144;    // 64*4096
static constexpr long ZERO_F   = OFF_LAT  + 64L * 4096;    // zero [0, ZERO_F)
static constexpr long OFF_SELM = ZERO_F;                   // 2048
static constexpr long OFF_SELI = OFF_SELM + 2048;          // 2048
static constexpr long OFF_SELT = OFF_SELI + 2048;          // 2048 (uint bits)
static constexpr long OFF_LOG  = OFF_SELT + 2048;          // 64*32*4096

// ---------------- types / helpers ----------------
typedef __attribute__((ext_vector_type(8))) short bf16x8;
typedef __attribute__((ext_vector_type(4))) float f32x4;

__device__ __forceinline__ unsigned fkey(float f) {
    unsigned u = __float_as_uint(f);
    return (u & 0x80000000u) ? ~u : (u | 0x80000000u);
}
__device__ __forceinline__ float kval(unsigned k) {
    unsigned u = (k & 0x80000000u) ? (k ^ 0x80000000u) : ~k;
    return __uint_as_float(u);
}
__device__ __forceinline__ unsigned short f2bf(float f) {
    __hip_bfloat16 h = __float2bfloat16(f);
    return *reinterpret_cast<unsigned short*>(&h);
}

// ============================================================
// Generic skinny GEMM: C[64 x M] += X[64 x K] * W[M x K]^T
// ============================================================
template <int TN>
__global__ __launch_bounds__(256) void gemm_xwt(
    const float* __restrict__ Xb, const float* __restrict__ Wb,
    float* __restrict__ Cb, int K, int ldX, int ldC, int kslice,
    long sXz, long sWz, long sCz)
{
    const float* X = Xb + (long)blockIdx.z * sXz;
    const float* W = Wb + (long)blockIdx.z * sWz;
    float*       C = Cb + (long)blockIdx.z * sCz;
    const int col0 = blockIdx.x * TN;
    const int k0   = blockIdx.y * kslice;

    __shared__ float Xs[32][68];
    __shared__ float Ws[32][TN + 4];

    const int t  = threadIdx.x;
    constexpr int CW = TN / 16;
    const int r0 = (t & 15) * 4;
    const int c0 = (t >> 4) * CW;

    float acc[4][CW];
#pragma unroll
    for (int j = 0; j < 4; ++j)
#pragma unroll
        for (int m = 0; m < CW; ++m) acc[j][m] = 0.f;

    for (int kt = k0; kt < k0 + kslice; kt += 32) {
#pragma unroll
        for (int i = 0; i < 2; ++i) {
            int f = t + i * 256;
            int r = f >> 3, k4 = (f & 7) * 4;
            float4 v = *(const float4*)(X + (long)r * ldX + kt + k4);
            Xs[k4][r] = v.x; Xs[k4 + 1][r] = v.y; Xs[k4 + 2][r] = v.z; Xs[k4 + 3][r] = v.w;
        }
#pragma unroll
        for (int i = 0; i < TN / 32; ++i) {
            int f = t + i * 256;
            int c = f >> 3, k4 = (f & 7) * 4;
            float4 v = *(const float4*)(W + (long)(col0 + c) * K + kt + k4);
            Ws[k4][c] = v.x; Ws[k4 + 1][c] = v.y; Ws[k4 + 2][c] = v.z; Ws[k4 + 3][c] = v.w;
        }
        __syncthreads();
#pragma unroll
        for (int k = 0; k < 32; ++k) {
            float4 a4 = *(const float4*)&Xs[k][r0];
            float av[4] = {a4.x, a4.y, a4.z, a4.w};
            float bv[CW];
#pragma unroll
            for (int m0 = 0; m0 < CW; m0 += 4) {
                float4 b4 = *(const float4*)&Ws[k][c0 + m0];
                bv[m0] = b4.x; bv[m0 + 1] = b4.y; bv[m0 + 2] = b4.z; bv[m0 + 3] = b4.w;
            }
#pragma unroll
            for (int j = 0; j < 4; ++j)
#pragma unroll
                for (int m = 0; m < CW; ++m) acc[j][m] += av[j] * bv[m];
        }
        __syncthreads();
    }
#pragma unroll
    for (int j = 0; j < 4; ++j)
#pragma unroll
        for (int m = 0; m < CW; ++m)
            atomicAdd(&C[(long)(r0 + j) * ldC + col0 + c0 + m], acc[j][m]);
}

// ============================================================
// RMS norm over rows (in-place)
// ============================================================
__global__ __launch_bounds__(256) void rms_rows(
    float* __restrict__ x, const float* __restrict__ w, int len)
{
    __shared__ float fred[4];
    float* row = x + (long)blockIdx.x * len;
    int t = threadIdx.x;
    float ss = 0.f;
    for (int l = t; l < len; l += 256) { float v = row[l]; ss += v * v; }
#pragma unroll
    for (int off = 32; off; off >>= 1) ss += __shfl_xor(ss, off, 64);
    if ((t & 63) == 0) fred[t >> 6] = ss;
    __syncthreads();
    ss = fred[0] + fred[1] + fred[2] + fred[3];
    float scale = rsqrtf(ss / (float)len + EPS_);
    for (int l = t; l < len; l += 256) row[l] = row[l] * scale * w[l];
}

// ============================================================
// RoPE on q
// ============================================================
__global__ __launch_bounds__(256) void rope_q(float* __restrict__ q,
                                              const int* __restrict__ cl)
{
    int n = blockIdx.x;
    float pos = (float)(cl[n] - 1);
    int t = threadIdx.x;
#pragma unroll
    for (int i = 0; i < 4; ++i) {
        int f = t + i * 256;
        int h = f >> 5, r = f & 31;
        float inv = exp2f(-(float)r * LOG2_1E4_OVER_32);
        float ang = pos * inv;
        float sn, cs;
        sincosf(ang, &sn, &cs);
        float* p = q + (long)n * 6144 + h * 192 + 128 + 2 * r;
        float x0 = p[0], x1 = p[1];
        p[0] = x0 * cs - x1 * sn;
        p[1] = x0 * sn + x1 * cs;
    }
}

// ============================================================
// KV post: RMS + RoPE + scatter into cache
// ============================================================
__global__ __launch_bounds__(256) void kv_post(
    const float* __restrict__ kvr, const float* __restrict__ wnorm,
    const int* __restrict__ cl, const int* __restrict__ smap,
    float* __restrict__ kvcache)
{
    __shared__ float s[192];
    __shared__ float fred[4];
    int n = blockIdx.x, t = threadIdx.x;
    float v = (t < 192) ? kvr[(long)n * 192 + t] : 0.f;
    float ss = v * v;
#pragma unroll
    for (int off = 32; off; off >>= 1) ss += __shfl_xor(ss, off, 64);
    if ((t & 63) == 0) fred[t >> 6] = ss;
    __syncthreads();
    ss = fred[0] + fred[1] + fred[2] + fred[3];
    float scale = rsqrtf(ss / 192.f + EPS_);
    if (t < 192) s[t] = v * scale * wnorm[t];
    __syncthreads();
    if (t < 32) {
        float pos = (float)(cl[n] - 1);
        float inv = exp2f(-(float)t * LOG2_1E4_OVER_32);
        float ang = pos * inv;
        float sn, cs;
        sincosf(ang, &sn, &cs);
        float x0 = s[128 + 2 * t], x1 = s[128 + 2 * t + 1];
        s[128 + 2 * t]     = x0 * cs - x1 * sn;
        s[128 + 2 * t + 1] = x0 * sn + x1 * cs;
    }
    __syncthreads();
    if (t < 192) kvcache[(long)smap[n] * 192 + t] = s[t];
}

// ============================================================
// MFMA attention logits: grid (32 chunks of 128 l, 64 n), 256 thr.
// S[h,l] = Q[h,:].KV[l,:] * SCALE, bf16 MFMA 16x16x32, f32 acc.
// LDS layout: row-major bf16, b128-unit XOR swizzle (u ^= row&7).
// ============================================================
__global__ __launch_bounds__(256) void attn_logits_mfma(
    const float* __restrict__ q, const float* __restrict__ kvc,
    const int* __restrict__ bt, const int* __restrict__ cl,
    float* __restrict__ logits)
{
    const int n = blockIdx.y, base = blockIdx.x * 128;
    const int ctx = cl[n];
    if (base >= ctx) return;

    __shared__ unsigned short qs[32 * 192];    // [h][d]
    __shared__ unsigned short kvs[128 * 192];  // [l][d]
    const int t = threadIdx.x;

    // stage Q: 32 rows x 24 b128-units
#pragma unroll
    for (int i = 0; i < 3; ++i) {
        int idx = t + i * 256;
        int h = idx / 24, u = idx - h * 24;
        const float* p = q + (long)n * 6144 + h * 192 + u * 8;
        float4 v0 = *(const float4*)p, v1 = *(const float4*)(p + 4);
        int su = u ^ (h & 7);
        bf16x8 s;
        s[0] = (short)f2bf(v0.x); s[1] = (short)f2bf(v0.y);
        s[2] = (short)f2bf(v0.z); s[3] = (short)f2bf(v0.w);
        s[4] = (short)f2bf(v1.x); s[5] = (short)f2bf(v1.y);
        s[6] = (short)f2bf(v1.z); s[7] = (short)f2bf(v1.w);
        *(bf16x8*)(qs + h * 192 + su * 8) = s;
    }
    // stage KV: 128 rows x 24 units (rows beyond ctx clamp to ctx-1)
#pragma unroll
    for (int i = 0; i < 12; ++i) {
        int idx = t + i * 256;
        int l = idx / 24, u = idx - l * 24;
        int gl = min(base + l, ctx - 1);
        int slot = bt[n * 64 + (gl >> 6)] * 64 + (gl & 63);
        const float* p = kvc + (long)slot * 192 + u * 8;
        float4 v0 = *(const float4*)p, v1 = *(const float4*)(p + 4);
        int su = u ^ (l & 7);
        bf16x8 s;
        s[0] = (short)f2bf(v0.x); s[1] = (short)f2bf(v0.y);
        s[2] = (short)f2bf(v0.z); s[3] = (short)f2bf(v0.w);
        s[4] = (short)f2bf(v1.x); s[5] = (short)f2bf(v1.y);
        s[6] = (short)f2bf(v1.z); s[7] = (short)f2bf(v1.w);
        *(bf16x8*)(kvs + l * 192 + su * 8) = s;
    }
    __syncthreads();

    const int w = t >> 6, lane = t & 63;
    const int m16 = lane & 15, qd = lane >> 4;

    f32x4 acc[2][2];
#pragma unroll
    for (int mt = 0; mt < 2; ++mt)
#pragma unroll
        for (int nt = 0; nt < 2; ++nt) acc[mt][nt] = (f32x4){0.f, 0.f, 0.f, 0.f};

#pragma unroll
    for (int ks = 0; ks < 6; ++ks) {
        int u = ks * 4 + qd;
        bf16x8 a[2], b[2];
#pragma unroll
        for (int mt = 0; mt < 2; ++mt) {
            int row = mt * 16 + m16;
            a[mt] = *(const bf16x8*)(qs + row * 192 + (u ^ (row & 7)) * 8);
        }
#pragma unroll
        for (int nt = 0; nt < 2; ++nt) {
            int row = (2 * w + nt) * 16 + m16;
            b[nt] = *(const bf16x8*)(kvs + row * 192 + (u ^ (row & 7)) * 8);
        }
#pragma unroll
        for (int mt = 0; mt < 2; ++mt)
#pragma unroll
            for (int nt = 0; nt < 2; ++nt)
                acc[mt][nt] = __builtin_amdgcn_mfma_f32_16x16x32_bf16(a[mt], b[nt], acc[mt][nt], 0, 0, 0);
    }
    // store: row=(lane>>4)*4+reg -> h, col=lane&15 -> l
#pragma unroll
    for (int mt = 0; mt < 2; ++mt)
#pragma unroll
        for (int nt = 0; nt < 2; ++nt) {
            int l = base + (2 * w + nt) * 16 + m16;
#pragma unroll
            for (int r = 0; r < 4; ++r) {
                int h = mt * 16 + qd * 4 + r;
                logits[((long)(n * 32 + h) << 12) + l] = acc[mt][nt][r] * SCALE_;
            }
        }
}

// ============================================================
// Exact top-1024 threshold via radix select + softmax stats
// ============================================================
__global__ __launch_bounds__(256) void select_topk(
    const float* __restrict__ logits, const int* __restrict__ cl,
    const float* __restrict__ sink, float* __restrict__ selm,
    float* __restrict__ seli, unsigned* __restrict__ selt)
{
    int nh = blockIdx.x, n = nh >> 5, h = nh & 31;
    int ctx = cl[n];
    const float* row = logits + ((long)nh << 12);

    __shared__ unsigned keys[4096];
    __shared__ int hist[256];
    __shared__ float fred[4];
    __shared__ unsigned s_pref;
    __shared__ int s_R;

    int t = threadIdx.x;
    float mx = -3.0e38f;
    for (int l = t; l < ctx; l += 256) {
        float v = row[l];
        keys[l] = fkey(v);
        mx = fmaxf(mx, v);
    }
#pragma unroll
    for (int off = 32; off; off >>= 1) mx = fmaxf(mx, __shfl_xor(mx, off, 64));
    if ((t & 63) == 0) fred[t >> 6] = mx;
    __syncthreads();
    mx = fmaxf(fmaxf(fred[0], fred[1]), fmaxf(fred[2], fred[3]));

    unsigned tau = 0;
    if (ctx > 1024) {
        unsigned pref = 0;
        int R = 1024;
        for (int round = 3; round >= 0; --round) {
            int sh = round * 8;
            hist[t] = 0;
            __syncthreads();
            for (int l = t; l < ctx; l += 256) {
                unsigned k = keys[l];
                bool match = (round == 3) || ((k >> (sh + 8)) == (pref >> (sh + 8)));
                if (match) atomicAdd(&hist[(k >> sh) & 255], 1);
            }
            __syncthreads();
            int cum = 0;
            for (int b = t + 1; b < 256; ++b) cum += hist[b];
            if (cum < R && cum + hist[t] >= R) {
                s_pref = pref | ((unsigned)t << sh);
                s_R = R - cum;
            }
            __syncthreads();
            pref = s_pref;
            R = s_R;
            __syncthreads();
        }
        tau = pref;
    }

    float m = fmaxf(mx, sink[h]);
    float part = 0.f;
    for (int l = t; l < ctx; l += 256) {
        unsigned k = keys[l];
        if (k >= tau) part += __expf(kval(k) - m);
    }
#pragma unroll
    for (int off = 32; off; off >>= 1) part += __shfl_xor(part, off, 64);
    __syncthreads();
    if ((t & 63) == 0) fred[t >> 6] = part;
    __syncthreads();
    if (t == 0) {
        float denom = fred[0] + fred[1] + fred[2] + fred[3] + __expf(sink[h] - m);
        selm[nh] = m;
        seli[nh] = 1.0f / denom;
        selt[nh] = tau;
    }
}

// ============================================================
// MFMA weighted sum: O[h,d] += sum_l P[h,l]*KV[l,d].
// grid (32 chunks of 128 l, 64 n), 256 thr. atomicAdd epilogue.
// P staged [h][l] bf16 swizzled; KV staged transposed [d][l].
// ============================================================
__global__ __launch_bounds__(256) void attn_wsum_mfma(
    const float* __restrict__ logits, const float* __restrict__ kvc,
    const int* __restrict__ bt, const int* __restrict__ cl,
    const float* __restrict__ selm, const float* __restrict__ seli,
    const unsigned* __restrict__ selt, float* __restrict__ o)
{
    const int n = blockIdx.y, base = blockIdx.x * 128;
    const int ctx = cl[n];
    if (base >= ctx) return;
    const int vcount = min(128, ctx - base);

    __shared__ unsigned short ps[32 * 128];    // [h][l]
    __shared__ unsigned short kvt[192 * 128];  // [d][l]
    const int t = threadIdx.x;

    // stage P: 32 rows x 16 b128-units
#pragma unroll
    for (int i = 0; i < 2; ++i) {
        int idx = t + i * 256;
        int h = idx >> 4, u = idx & 15;
        int nh = n * 32 + h;
        float m = selm[nh], inv = seli[nh];
        unsigned tau = selt[nh];
        const float* lp = logits + ((long)nh << 12) + base + u * 8;
        float4 v0 = *(const float4*)lp, v1 = *(const float4*)(lp + 4);
        float vv[8] = {v0.x, v0.y, v0.z, v0.w, v1.x, v1.y, v1.z, v1.w};
        bf16x8 s;
#pragma unroll
        for (int j = 0; j < 8; ++j) {
            int ll = u * 8 + j;
            float p = 0.f;
            if (ll < vcount && fkey(vv[j]) >= tau) p = __expf(vv[j] - m) * inv;
            s[j] = (short)f2bf(p);
        }
        int su = u ^ (h & 7);
        *(bf16x8*)(ps + h * 128 + su * 8) = s;
    }
    // stage KV transposed: thread reads float4 (4 d of one l), writes 4 b16
#pragma unroll
    for (int i = 0; i < 24; ++i) {
        int f = t + i * 256;
        int l = f & 127, d4 = f >> 7;
        int gl = min(base + l, ctx - 1);
        int slot = bt[n * 64 + (gl >> 6)] * 64 + (gl & 63);
        float4 v = *(const float4*)(kvc + (long)slot * 192 + d4 * 4);
        float vv[4] = {v.x, v.y, v.z, v.w};
#pragma unroll
        for (int e = 0; e < 4; ++e) {
            int d = d4 * 4 + e;
            int scol = (l & 7) | ((((l >> 3) ^ (d & 7)) & 15) << 3);
            kvt[d * 128 + scol] = f2bf(vv[e]);
        }
    }
    __syncthreads();

    const int w = t >> 6, lane = t & 63;
    const int m16 = lane & 15, qd = lane >> 4;

    f32x4 acc[2][3];
#pragma unroll
    for (int mt = 0; mt < 2; ++mt)
#pragma unroll
        for (int nt = 0; nt < 3; ++nt) acc[mt][nt] = (f32x4){0.f, 0.f, 0.f, 0.f};

#pragma unroll
    for (int ks = 0; ks < 4; ++ks) {
        int u = ks * 4 + qd;
        bf16x8 a[2], b[3];
#pragma unroll
        for (int mt = 0; mt < 2; ++mt) {
            int row = mt * 16 + m16;
            a[mt] = *(const bf16x8*)(ps + row * 128 + (u ^ (row & 7)) * 8);
        }
#pragma unroll
        for (int nt = 0; nt < 3; ++nt) {
            int row = (3 * w + nt) * 16 + m16;   // d row
            b[nt] = *(const bf16x8*)(kvt + row * 128 + (u ^ (row & 7)) * 8);
        }
#pragma unroll
        for (int mt = 0; mt < 2; ++mt)
#pragma unroll
            for (int nt = 0; nt < 3; ++nt)
                acc[mt][nt] = __builtin_amdgcn_mfma_f32_16x16x32_bf16(a[mt], b[nt], acc[mt][nt], 0, 0, 0);
    }
#pragma unroll
    for (int mt = 0; mt < 2; ++mt)
#pragma unroll
        for (int nt = 0; nt < 3; ++nt) {
            int d = (3 * w + nt) * 16 + m16;
#pragma unroll
            for (int r = 0; r < 4; ++r) {
                int h = mt * 16 + qd * 4 + r;
                atomicAdd(&o[(long)n * 6144 + h * 192 + d], acc[mt][nt][r]);
            }
        }
}

// ============================================================
// launch
// ============================================================
extern "C" void kernel_launch(void* const* d_in, const int* in_sizes, int n_in,
                              void* d_out, int out_size, void* d_ws, size_t ws_size,
                              hipStream_t stream)
{
    const float* x    = (const float*)d_in[0];
    float*       kvc  = (float*)d_in[1];
    const int*   bt   = (const int*)d_in[2];
    const int*   cl   = (const int*)d_in[3];
    const int*   smap = (const int*)d_in[4];
    const float* wqa  = (const float*)d_in[5];
    const float* qnw  = (const float*)d_in[6];
    const float* wqb  = (const float*)d_in[7];
    const float* wkv  = (const float*)d_in[8];
    const float* kvnw = (const float*)d_in[9];
    const float* woa  = (const float*)d_in[10];
    const float* wob  = (const float*)d_in[11];
    const float* sink = (const float*)d_in[12];
    float* ws  = (float*)d_ws;
    float* out = (float*)d_out;

    hipMemsetAsync(ws, 0, (size_t)ZERO_F * sizeof(float), stream);
    hipMemsetAsync(out, 0, (size_t)out_size * sizeof(float), stream);

    // q low-rank: qlat = x @ wq_a^T   (64x1536, K=4096)
    gemm_xwt<128><<<dim3(12, 8, 1), 256, 0, stream>>>(x, wqa, ws + OFF_QLAT,
                                                      4096, 4096, 1536, 512, 0, 0, 0);
    rms_rows<<<64, 256, 0, stream>>>(ws + OFF_QLAT, qnw, 1536);
    // q = qlat @ wq_b^T   (64x6144, K=1536)
    gemm_xwt<128><<<dim3(48, 4, 1), 256, 0, stream>>>(ws + OFF_QLAT, wqb, ws + OFF_Q,
                                                      1536, 1536, 6144, 384, 0, 0, 0);
    rope_q<<<64, 256, 0, stream>>>(ws + OFF_Q, cl);
    // kv = x @ wkv^T   (64x192, K=4096)
    gemm_xwt<64><<<dim3(3, 8, 1), 256, 0, stream>>>(x, wkv, ws + OFF_KVR,
                                                    4096, 4096, 192, 512, 0, 0, 0);
    kv_post<<<64, 256, 0, stream>>>(ws + OFF_KVR, kvnw, cl, smap, kvc);
    // attention (MFMA bf16)
    attn_logits_mfma<<<dim3(32, 64), 256, 0, stream>>>(ws + OFF_Q, kvc, bt, cl,
                                                       ws + OFF_LOG);
    select_topk<<<2048, 256, 0, stream>>>(ws + OFF_LOG, cl, sink,
                                          ws + OFF_SELM, ws + OFF_SELI,
                                          (unsigned*)(ws + OFF_SELT));
    attn_wsum_mfma<<<dim3(32, 64), 256, 0, stream>>>(ws + OFF_LOG, kvc, bt, cl,
                                                     ws + OFF_SELM, ws + OFF_SELI,
                                                     (unsigned*)(ws + OFF_SELT),
                                                     ws + OFF_O);
    // grouped wo_a: lat[n, g*512+o] = og[n,g,:] @ wo_a[g]^T  (8 batches, 64x512, K=768)
    gemm_xwt<128><<<dim3(4, 2, 8), 256, 0, stream>>>(ws + OFF_O, woa, ws + OFF_LAT,
                                                     768, 6144, 4096, 384,
                                                     768, 512L * 768, 512);
    // out = lat @ wo_b^T  (64x4096, K=4096) — accumulate into d_out (f32)
    gemm_xwt<128><<<dim3(32, 8, 1), 256, 0, stream>>>(ws + OFF_LAT, wob, out,
                                                      4096, 4096, 4096, 512, 0, 0, 0);
}

// Round 4
// 543.960 us; speedup vs baseline: 2.1182x; 1.4122x over previous
//
#include <hip/hip_runtime.h>
#include <hip/hip_bf16.h>

// ---------------- problem constants ----------------
static constexpr float EPS_   = 1e-6f;
static constexpr float SCALE_ = 0.07216878364870323f;  // 192^-0.5
static constexpr float LOG2_1E4_OVER_32 = 13.287712379549449f / 32.0f;

// ---------------- workspace layout (float offsets) ----------------
static constexpr long OFF_QLAT = 0;                        // 64*1536
static constexpr long OFF_Q    = OFF_QLAT + 64L * 1536;    // 64*6144
static constexpr long OFF_KVR  = OFF_Q    + 64L * 6144;    // 64*192
static constexpr long OFF_O    = OFF_KVR  + 64L * 192;     // 64*6144
static constexpr long OFF_LAT  = OFF_O    + 64L * 6144;    // 64*4096
static constexpr long ZERO_F   = OFF_LAT  + 64L * 4096;    // zero [0, ZERO_F)
static constexpr long OFF_SELM = ZERO_F;                   // 2048
static constexpr long OFF_SELI = OFF_SELM + 2048;          // 2048
static constexpr long OFF_SELT = OFF_SELI + 2048;          // 2048 (uint bits)
static constexpr long OFF_LOG  = OFF_SELT + 2048;          // 64*32*4096

// ---------------- types / helpers ----------------
typedef __attribute__((ext_vector_type(8))) short bf16x8;
typedef __attribute__((ext_vector_type(4))) float f32x4;

__device__ __forceinline__ unsigned fkey(float f) {
    unsigned u = __float_as_uint(f);
    return (u & 0x80000000u) ? ~u : (u | 0x80000000u);
}
__device__ __forceinline__ float kval(unsigned k) {
    unsigned u = (k & 0x80000000u) ? (k ^ 0x80000000u) : ~k;
    return __uint_as_float(u);
}
__device__ __forceinline__ unsigned short f2bf(float f) {
    __hip_bfloat16 h = __float2bfloat16(f);
    return *reinterpret_cast<unsigned short*>(&h);
}
__device__ __forceinline__ bf16x8 pack8(float4 v0, float4 v1) {
    bf16x8 s;
    s[0] = (short)f2bf(v0.x); s[1] = (short)f2bf(v0.y);
    s[2] = (short)f2bf(v0.z); s[3] = (short)f2bf(v0.w);
    s[4] = (short)f2bf(v1.x); s[5] = (short)f2bf(v1.y);
    s[6] = (short)f2bf(v1.z); s[7] = (short)f2bf(v1.w);
    return s;
}

// ============================================================
// MFMA skinny GEMM: C[64 x M] += X[64 x K] * W[M x K]^T (bf16 in, f32 acc)
// grid: (M/TN, K/kslice, batch); 256 threads (4 waves); atomicAdd epilogue.
// LDS [row][k] bf16, BK=64, b128-unit XOR swizzle (u ^= row&7).
// ============================================================
template <int TN>
__global__ __launch_bounds__(256) void gemm_mfma(
    const float* __restrict__ Xb, const float* __restrict__ Wb,
    float* __restrict__ Cb, int K, int ldX, int ldC, int kslice,
    long sXz, long sWz, long sCz)
{
    const float* X = Xb + (long)blockIdx.z * sXz;
    const float* W = Wb + (long)blockIdx.z * sWz;
    float*       C = Cb + (long)blockIdx.z * sCz;
    const int col0 = blockIdx.x * TN;
    const int k0   = blockIdx.y * kslice;

    __shared__ unsigned short Xs[64 * 64];
    __shared__ unsigned short Ws[TN * 64];

    const int t = threadIdx.x;
    const int w = t >> 6, lane = t & 63;
    const int m16 = lane & 15, qd = lane >> 4;
    constexpr int NT = TN / 64;          // n-tiles per wave (2 or 1)

    f32x4 acc[4][NT];
#pragma unroll
    for (int mt = 0; mt < 4; ++mt)
#pragma unroll
        for (int nt = 0; nt < NT; ++nt) acc[mt][nt] = (f32x4){0.f, 0.f, 0.f, 0.f};

    for (int kt = k0; kt < k0 + kslice; kt += 64) {
        // stage X: 64 rows x 8 units
#pragma unroll
        for (int i = 0; i < 2; ++i) {
            int idx = t + i * 256;
            int r = idx >> 3, u = idx & 7;
            const float* p = X + (long)r * ldX + kt + u * 8;
            float4 v0 = *(const float4*)p, v1 = *(const float4*)(p + 4);
            *(bf16x8*)(Xs + r * 64 + (u ^ (r & 7)) * 8) = pack8(v0, v1);
        }
        // stage W: TN rows x 8 units
#pragma unroll
        for (int i = 0; i < TN / 32; ++i) {
            int idx = t + i * 256;
            int r = idx >> 3, u = idx & 7;
            const float* p = W + (long)(col0 + r) * K + kt + u * 8;
            float4 v0 = *(const float4*)p, v1 = *(const float4*)(p + 4);
            *(bf16x8*)(Ws + r * 64 + (u ^ (r & 7)) * 8) = pack8(v0, v1);
        }
        __syncthreads();
#pragma unroll
        for (int ks = 0; ks < 2; ++ks) {
            int u = ks * 4 + qd;
            bf16x8 a[4], b[NT];
#pragma unroll
            for (int mt = 0; mt < 4; ++mt) {
                int row = mt * 16 + m16;
                a[mt] = *(const bf16x8*)(Xs + row * 64 + (u ^ (row & 7)) * 8);
            }
#pragma unroll
            for (int nt = 0; nt < NT; ++nt) {
                int row = (w * NT + nt) * 16 + m16;
                b[nt] = *(const bf16x8*)(Ws + row * 64 + (u ^ (row & 7)) * 8);
            }
#pragma unroll
            for (int mt = 0; mt < 4; ++mt)
#pragma unroll
                for (int nt = 0; nt < NT; ++nt)
                    acc[mt][nt] = __builtin_amdgcn_mfma_f32_16x16x32_bf16(a[mt], b[nt], acc[mt][nt], 0, 0, 0);
        }
        __syncthreads();
    }
#pragma unroll
    for (int mt = 0; mt < 4; ++mt)
#pragma unroll
        for (int nt = 0; nt < NT; ++nt) {
            int col = col0 + (w * NT + nt) * 16 + m16;
#pragma unroll
            for (int r = 0; r < 4; ++r) {
                int row = mt * 16 + qd * 4 + r;
                atomicAdd(&C[(long)row * ldC + col], acc[mt][nt][r]);
            }
        }
}

// ============================================================
// RMS norm over rows (in-place)
// ============================================================
__global__ __launch_bounds__(256) void rms_rows(
    float* __restrict__ x, const float* __restrict__ w, int len)
{
    __shared__ float fred[4];
    float* row = x + (long)blockIdx.x * len;
    int t = threadIdx.x;
    float ss = 0.f;
    for (int l = t; l < len; l += 256) { float v = row[l]; ss += v * v; }
#pragma unroll
    for (int off = 32; off; off >>= 1) ss += __shfl_xor(ss, off, 64);
    if ((t & 63) == 0) fred[t >> 6] = ss;
    __syncthreads();
    ss = fred[0] + fred[1] + fred[2] + fred[3];
    float scale = rsqrtf(ss / (float)len + EPS_);
    for (int l = t; l < len; l += 256) row[l] = row[l] * scale * w[l];
}

// ============================================================
// RoPE on q
// ============================================================
__global__ __launch_bounds__(256) void rope_q(float* __restrict__ q,
                                              const int* __restrict__ cl)
{
    int n = blockIdx.x;
    float pos = (float)(cl[n] - 1);
    int t = threadIdx.x;
#pragma unroll
    for (int i = 0; i < 4; ++i) {
        int f = t + i * 256;
        int h = f >> 5, r = f & 31;
        float inv = exp2f(-(float)r * LOG2_1E4_OVER_32);
        float ang = pos * inv;
        float sn, cs;
        sincosf(ang, &sn, &cs);
        float* p = q + (long)n * 6144 + h * 192 + 128 + 2 * r;
        float x0 = p[0], x1 = p[1];
        p[0] = x0 * cs - x1 * sn;
        p[1] = x0 * sn + x1 * cs;
    }
}

// ============================================================
// KV post: RMS + RoPE + scatter into cache
// ============================================================
__global__ __launch_bounds__(256) void kv_post(
    const float* __restrict__ kvr, const float* __restrict__ wnorm,
    const int* __restrict__ cl, const int* __restrict__ smap,
    float* __restrict__ kvcache)
{
    __shared__ float s[192];
    __shared__ float fred[4];
    int n = blockIdx.x, t = threadIdx.x;
    float v = (t < 192) ? kvr[(long)n * 192 + t] : 0.f;
    float ss = v * v;
#pragma unroll
    for (int off = 32; off; off >>= 1) ss += __shfl_xor(ss, off, 64);
    if ((t & 63) == 0) fred[t >> 6] = ss;
    __syncthreads();
    ss = fred[0] + fred[1] + fred[2] + fred[3];
    float scale = rsqrtf(ss / 192.f + EPS_);
    if (t < 192) s[t] = v * scale * wnorm[t];
    __syncthreads();
    if (t < 32) {
        float pos = (float)(cl[n] - 1);
        float inv = exp2f(-(float)t * LOG2_1E4_OVER_32);
        float ang = pos * inv;
        float sn, cs;
        sincosf(ang, &sn, &cs);
        float x0 = s[128 + 2 * t], x1 = s[128 + 2 * t + 1];
        s[128 + 2 * t]     = x0 * cs - x1 * sn;
        s[128 + 2 * t + 1] = x0 * sn + x1 * cs;
    }
    __syncthreads();
    if (t < 192) kvcache[(long)smap[n] * 192 + t] = s[t];
}

// ============================================================
// MFMA attention logits: grid (32 chunks of 128 l, 64 n), 256 thr.
// ============================================================
__global__ __launch_bounds__(256) void attn_logits_mfma(
    const float* __restrict__ q, const float* __restrict__ kvc,
    const int* __restrict__ bt, const int* __restrict__ cl,
    float* __restrict__ logits)
{
    const int n = blockIdx.y, base = blockIdx.x * 128;
    const int ctx = cl[n];
    if (base >= ctx) return;

    __shared__ unsigned short qs[32 * 192];    // [h][d]
    __shared__ unsigned short kvs[128 * 192];  // [l][d]
    const int t = threadIdx.x;

#pragma unroll
    for (int i = 0; i < 3; ++i) {
        int idx = t + i * 256;
        int h = idx / 24, u = idx - h * 24;
        const float* p = q + (long)n * 6144 + h * 192 + u * 8;
        float4 v0 = *(const float4*)p, v1 = *(const float4*)(p + 4);
        *(bf16x8*)(qs + h * 192 + (u ^ (h & 7)) * 8) = pack8(v0, v1);
    }
#pragma unroll
    for (int i = 0; i < 12; ++i) {
        int idx = t + i * 256;
        int l = idx / 24, u = idx - l * 24;
        int gl = min(base + l, ctx - 1);
        int slot = bt[n * 64 + (gl >> 6)] * 64 + (gl & 63);
        const float* p = kvc + (long)slot * 192 + u * 8;
        float4 v0 = *(const float4*)p, v1 = *(const float4*)(p + 4);
        *(bf16x8*)(kvs + l * 192 + (u ^ (l & 7)) * 8) = pack8(v0, v1);
    }
    __syncthreads();

    const int w = t >> 6, lane = t & 63;
    const int m16 = lane & 15, qd = lane >> 4;

    f32x4 acc[2][2];
#pragma unroll
    for (int mt = 0; mt < 2; ++mt)
#pragma unroll
        for (int nt = 0; nt < 2; ++nt) acc[mt][nt] = (f32x4){0.f, 0.f, 0.f, 0.f};

#pragma unroll
    for (int ks = 0; ks < 6; ++ks) {
        int u = ks * 4 + qd;
        bf16x8 a[2], b[2];
#pragma unroll
        for (int mt = 0; mt < 2; ++mt) {
            int row = mt * 16 + m16;
            a[mt] = *(const bf16x8*)(qs + row * 192 + (u ^ (row & 7)) * 8);
        }
#pragma unroll
        for (int nt = 0; nt < 2; ++nt) {
            int row = (2 * w + nt) * 16 + m16;
            b[nt] = *(const bf16x8*)(kvs + row * 192 + (u ^ (row & 7)) * 8);
        }
#pragma unroll
        for (int mt = 0; mt < 2; ++mt)
#pragma unroll
            for (int nt = 0; nt < 2; ++nt)
                acc[mt][nt] = __builtin_amdgcn_mfma_f32_16x16x32_bf16(a[mt], b[nt], acc[mt][nt], 0, 0, 0);
    }
#pragma unroll
    for (int mt = 0; mt < 2; ++mt)
#pragma unroll
        for (int nt = 0; nt < 2; ++nt) {
            int l = base + (2 * w + nt) * 16 + m16;
#pragma unroll
            for (int r = 0; r < 4; ++r) {
                int h = mt * 16 + qd * 4 + r;
                logits[((long)(n * 32 + h) << 12) + l] = acc[mt][nt][r] * SCALE_;
            }
        }
}

// ============================================================
// Exact top-1024 threshold via radix select + softmax stats
// ============================================================
__global__ __launch_bounds__(256) void select_topk(
    const float* __restrict__ logits, const int* __restrict__ cl,
    const float* __restrict__ sink, float* __restrict__ selm,
    float* __restrict__ seli, unsigned* __restrict__ selt)
{
    int nh = blockIdx.x, n = nh >> 5, h = nh & 31;
    int ctx = cl[n];
    const float* row = logits + ((long)nh << 12);

    __shared__ unsigned keys[4096];
    __shared__ int hist[256];
    __shared__ float fred[4];
    __shared__ unsigned s_pref;
    __shared__ int s_R;

    int t = threadIdx.x;
    float mx = -3.0e38f;
    for (int l = t; l < ctx; l += 256) {
        float v = row[l];
        keys[l] = fkey(v);
        mx = fmaxf(mx, v);
    }
#pragma unroll
    for (int off = 32; off; off >>= 1) mx = fmaxf(mx, __shfl_xor(mx, off, 64));
    if ((t & 63) == 0) fred[t >> 6] = mx;
    __syncthreads();
    mx = fmaxf(fmaxf(fred[0], fred[1]), fmaxf(fred[2], fred[3]));

    unsigned tau = 0;
    if (ctx > 1024) {
        unsigned pref = 0;
        int R = 1024;
        for (int round = 3; round >= 0; --round) {
            int sh = round * 8;
            hist[t] = 0;
            __syncthreads();
            for (int l = t; l < ctx; l += 256) {
                unsigned k = keys[l];
                bool match = (round == 3) || ((k >> (sh + 8)) == (pref >> (sh + 8)));
                if (match) atomicAdd(&hist[(k >> sh) & 255], 1);
            }
            __syncthreads();
            int cum = 0;
            for (int b = t + 1; b < 256; ++b) cum += hist[b];
            if (cum < R && cum + hist[t] >= R) {
                s_pref = pref | ((unsigned)t << sh);
                s_R = R - cum;
            }
            __syncthreads();
            pref = s_pref;
            R = s_R;
            __syncthreads();
        }
        tau = pref;
    }

    float m = fmaxf(mx, sink[h]);
    float part = 0.f;
    for (int l = t; l < ctx; l += 256) {
        unsigned k = keys[l];
        if (k >= tau) part += __expf(kval(k) - m);
    }
#pragma unroll
    for (int off = 32; off; off >>= 1) part += __shfl_xor(part, off, 64);
    __syncthreads();
    if ((t & 63) == 0) fred[t >> 6] = part;
    __syncthreads();
    if (t == 0) {
        float denom = fred[0] + fred[1] + fred[2] + fred[3] + __expf(sink[h] - m);
        selm[nh] = m;
        seli[nh] = 1.0f / denom;
        selt[nh] = tau;
    }
}

// ============================================================
// MFMA weighted sum
// ============================================================
__global__ __launch_bounds__(256) void attn_wsum_mfma(
    const float* __restrict__ logits, const float* __restrict__ kvc,
    const int* __restrict__ bt, const int* __restrict__ cl,
    const float* __restrict__ selm, const float* __restrict__ seli,
    const unsigned* __restrict__ selt, float* __restrict__ o)
{
    const int n = blockIdx.y, base = blockIdx.x * 128;
    const int ctx = cl[n];
    if (base >= ctx) return;
    const int vcount = min(128, ctx - base);

    __shared__ unsigned short ps[32 * 128];    // [h][l]
    __shared__ unsigned short kvt[192 * 128];  // [d][l]
    const int t = threadIdx.x;

#pragma unroll
    for (int i = 0; i < 2; ++i) {
        int idx = t + i * 256;
        int h = idx >> 4, u = idx & 15;
        int nh = n * 32 + h;
        float m = selm[nh], inv = seli[nh];
        unsigned tau = selt[nh];
        const float* lp = logits + ((long)nh << 12) + base + u * 8;
        float4 v0 = *(const float4*)lp, v1 = *(const float4*)(lp + 4);
        float vv[8] = {v0.x, v0.y, v0.z, v0.w, v1.x, v1.y, v1.z, v1.w};
        bf16x8 s;
#pragma unroll
        for (int j = 0; j < 8; ++j) {
            int ll = u * 8 + j;
            float p = 0.f;
            if (ll < vcount && fkey(vv[j]) >= tau) p = __expf(vv[j] - m) * inv;
            s[j] = (short)f2bf(p);
        }
        *(bf16x8*)(ps + h * 128 + (u ^ (h & 7)) * 8) = s;
    }
#pragma unroll
    for (int i = 0; i < 24; ++i) {
        int f = t + i * 256;
        int l = f & 127, d4 = f >> 7;
        int gl = min(base + l, ctx - 1);
        int slot = bt[n * 64 + (gl >> 6)] * 64 + (gl & 63);
        float4 v = *(const float4*)(kvc + (long)slot * 192 + d4 * 4);
        float vv[4] = {v.x, v.y, v.z, v.w};
#pragma unroll
        for (int e = 0; e < 4; ++e) {
            int d = d4 * 4 + e;
            int scol = (l & 7) | ((((l >> 3) ^ (d & 7)) & 15) << 3);
            kvt[d * 128 + scol] = f2bf(vv[e]);
        }
    }
    __syncthreads();

    const int w = t >> 6, lane = t & 63;
    const int m16 = lane & 15, qd = lane >> 4;

    f32x4 acc[2][3];
#pragma unroll
    for (int mt = 0; mt < 2; ++mt)
#pragma unroll
        for (int nt = 0; nt < 3; ++nt) acc[mt][nt] = (f32x4){0.f, 0.f, 0.f, 0.f};

#pragma unroll
    for (int ks = 0; ks < 4; ++ks) {
        int u = ks * 4 + qd;
        bf16x8 a[2], b[3];
#pragma unroll
        for (int mt = 0; mt < 2; ++mt) {
            int row = mt * 16 + m16;
            a[mt] = *(const bf16x8*)(ps + row * 128 + (u ^ (row & 7)) * 8);
        }
#pragma unroll
        for (int nt = 0; nt < 3; ++nt) {
            int row = (3 * w + nt) * 16 + m16;
            b[nt] = *(const bf16x8*)(kvt + row * 128 + (u ^ (row & 7)) * 8);
        }
#pragma unroll
        for (int mt = 0; mt < 2; ++mt)
#pragma unroll
            for (int nt = 0; nt < 3; ++nt)
                acc[mt][nt] = __builtin_amdgcn_mfma_f32_16x16x32_bf16(a[mt], b[nt], acc[mt][nt], 0, 0, 0);
    }
#pragma unroll
    for (int mt = 0; mt < 2; ++mt)
#pragma unroll
        for (int nt = 0; nt < 3; ++nt) {
            int d = (3 * w + nt) * 16 + m16;
#pragma unroll
            for (int r = 0; r < 4; ++r) {
                int h = mt * 16 + qd * 4 + r;
                atomicAdd(&o[(long)n * 6144 + h * 192 + d], acc[mt][nt][r]);
            }
        }
}

// ============================================================
// launch
// ============================================================
extern "C" void kernel_launch(void* const* d_in, const int* in_sizes, int n_in,
                              void* d_out, int out_size, void* d_ws, size_t ws_size,
                              hipStream_t stream)
{
    const float* x    = (const float*)d_in[0];
    float*       kvc  = (float*)d_in[1];
    const int*   bt   = (const int*)d_in[2];
    const int*   cl   = (const int*)d_in[3];
    const int*   smap = (const int*)d_in[4];
    const float* wqa  = (const float*)d_in[5];
    const float* qnw  = (const float*)d_in[6];
    const float* wqb  = (const float*)d_in[7];
    const float* wkv  = (const float*)d_in[8];
    const float* kvnw = (const float*)d_in[9];
    const float* woa  = (const float*)d_in[10];
    const float* wob  = (const float*)d_in[11];
    const float* sink = (const float*)d_in[12];
    float* ws  = (float*)d_ws;
    float* out = (float*)d_out;

    hipMemsetAsync(ws, 0, (size_t)ZERO_F * sizeof(float), stream);
    hipMemsetAsync(out, 0, (size_t)out_size * sizeof(float), stream);

    // qlat = x @ wq_a^T   (64x1536, K=4096)
    gemm_mfma<128><<<dim3(12, 16, 1), 256, 0, stream>>>(x, wqa, ws + OFF_QLAT,
                                                        4096, 4096, 1536, 256, 0, 0, 0);
    rms_rows<<<64, 256, 0, stream>>>(ws + OFF_QLAT, qnw, 1536);
    // q = qlat @ wq_b^T   (64x6144, K=1536)
    gemm_mfma<128><<<dim3(48, 6, 1), 256, 0, stream>>>(ws + OFF_QLAT, wqb, ws + OFF_Q,
                                                       1536, 1536, 6144, 256, 0, 0, 0);
    rope_q<<<64, 256, 0, stream>>>(ws + OFF_Q, cl);
    // kv = x @ wkv^T   (64x192, K=4096)
    gemm_mfma<64><<<dim3(3, 32, 1), 256, 0, stream>>>(x, wkv, ws + OFF_KVR,
                                                      4096, 4096, 192, 128, 0, 0, 0);
    kv_post<<<64, 256, 0, stream>>>(ws + OFF_KVR, kvnw, cl, smap, kvc);
    // attention (MFMA bf16)
    attn_logits_mfma<<<dim3(32, 64), 256, 0, stream>>>(ws + OFF_Q, kvc, bt, cl,
                                                       ws + OFF_LOG);
    select_topk<<<2048, 256, 0, stream>>>(ws + OFF_LOG, cl, sink,
                                          ws + OFF_SELM, ws + OFF_SELI,
                                          (unsigned*)(ws + OFF_SELT));
    attn_wsum_mfma<<<dim3(32, 64), 256, 0, stream>>>(ws + OFF_LOG, kvc, bt, cl,
                                                     ws + OFF_SELM, ws + OFF_SELI,
                                                     (unsigned*)(ws + OFF_SELT),
                                                     ws + OFF_O);
    // grouped wo_a: 8 batches, 64x512, K=768
    gemm_mfma<128><<<dim3(4, 3, 8), 256, 0, stream>>>(ws + OFF_O, woa, ws + OFF_LAT,
                                                      768, 6144, 4096, 256,
                                                      768, 512L * 768, 512);
    // out = lat @ wo_b^T  (64x4096, K=4096)
    gemm_mfma<128><<<dim3(32, 8, 1), 256, 0, stream>>>(ws + OFF_LAT, wob, out,
                                                       4096, 4096, 4096, 512, 0, 0, 0);
}